// Round 10
// baseline (131.143 us; speedup 1.0000x reference)
//
#include <hip/hip_runtime.h>
#include <stdint.h>

#define NTOT 8192
#define BHALF 4096
#define DZ 512
#define DC 128
#define TEMPV 0.5f
#define FIXM 16.0f
#define LOG2E 1.44269504f
#define FM2 23.08312065f   // FIXM * LOG2E
#define SCALE1 0x7F7F7F7F  // e8m0 unit scales

typedef __attribute__((ext_vector_type(4))) float f32x4;
typedef __attribute__((ext_vector_type(16))) float f32x16;
typedef __attribute__((ext_vector_type(4))) float floatx4;
typedef __attribute__((ext_vector_type(2))) unsigned long ulong2v;  // 16B chunk
typedef __attribute__((ext_vector_type(8))) int int8v;              // 32B MFMA operand
typedef __attribute__((ext_vector_type(4))) unsigned int uint4v;

// MX-scaled fp8 MFMA, 32x32x64, unit scales. cbsz=0/blgp=0 -> FP8 e4m3 A and B.
#define MFMAS32(a, b, c) \
  __builtin_amdgcn_mfma_scale_f32_32x32x64_f8f6f4((a), (b), (c), 0, 0, 0, SCALE1, 0, SCALE1)

// counted vmcnt + raw barrier (no vmcnt(0) drain in the main loop)
#define WAITV(N) asm volatile("s_waitcnt vmcnt(" #N ")" ::: "memory")
#define BARRIER() asm volatile("s_barrier" ::: "memory")

__device__ __forceinline__ uint32_t pk4_e4m3(float f0, float f1, float f2, float f3) {
  int w = 0;
  w = __builtin_amdgcn_cvt_pk_fp8_f32(f0, f1, w, false);
  w = __builtin_amdgcn_cvt_pk_fp8_f32(f2, f3, w, true);
  return (uint32_t)w;
}

__device__ __forceinline__ int8v mk8(ulong2v lo, ulong2v hi) {
  int8v r;
  ((ulong2v*)&r)[0] = lo;
  ((ulong2v*)&r)[1] = hi;
  return r;
}

__device__ __forceinline__ void gll(const uint8_t* src, uint8_t* dst) {
  __builtin_amdgcn_global_load_lds((const __attribute__((address_space(1))) void*)src,
                                   (__attribute__((address_space(3))) void*)dst, 16, 0, 0);
}

// ---------------- convert: fp32 -> fp8 e4m3 (frag-pair-tiled) + fused pos dots ----------------
// R21 single-pass version (verified): one wave per pair-row; z read once; pos dot via
// shfl_xor(.,32) cross-half products. c-section verified mapping.
__global__ void convert_kernel(const float* __restrict__ z_i, const float* __restrict__ z_j,
                               const float* __restrict__ c_i, const float* __restrict__ c_j,
                               uint8_t* __restrict__ zbT, uint8_t* __restrict__ cbT,
                               float* __restrict__ pos2, float* __restrict__ out) {
  if (blockIdx.x < 1024) {
    const int p    = blockIdx.x * 4 + (threadIdx.x >> 6);   // 0..4095
    const int lane = threadIdx.x & 63;
    const int half = lane >> 5;          // 0: z_i row p, 1: z_j row p (global row p+4096)
    const int l    = lane & 31;
    const int cc   = l >> 2;
    const int lq   = l & 3;
    const int k0   = cc * 64 + lq * 8;

    const float* src = half ? (z_j + (size_t)p * DZ) : (z_i + (size_t)p * DZ);
    floatx4 a0 = *(const floatx4*)(src + k0);
    floatx4 a1 = *(const floatx4*)(src + k0 + 4);
    floatx4 b0 = *(const floatx4*)(src + k0 + 32);
    floatx4 b1 = *(const floatx4*)(src + k0 + 36);

    uint4v o;
    o.x = pk4_e4m3(a0[0], a0[1], a0[2], a0[3]);
    o.y = pk4_e4m3(a1[0], a1[1], a1[2], a1[3]);
    o.z = pk4_e4m3(b0[0], b0[1], b0[2], b0[3]);
    o.w = pk4_e4m3(b1[0], b1[1], b1[2], b1[3]);
    const int row = half ? (p + BHALF) : p;
    const size_t ci = (((size_t)(row >> 4) * 8 + cc) * 64 + (size_t)lq * 16 + (row & 15));
    *(uint4v*)(zbT + ci * 16) = o;

    float d = 0.0f;
#pragma unroll
    for (int m = 0; m < 4; ++m) d = __builtin_fmaf(a0[m], __shfl_xor(a0[m], 32), d);
#pragma unroll
    for (int m = 0; m < 4; ++m) d = __builtin_fmaf(a1[m], __shfl_xor(a1[m], 32), d);
#pragma unroll
    for (int m = 0; m < 4; ++m) d = __builtin_fmaf(b0[m], __shfl_xor(b0[m], 32), d);
#pragma unroll
    for (int m = 0; m < 4; ++m) d = __builtin_fmaf(b1[m], __shfl_xor(b1[m], 32), d);
#pragma unroll
    for (int off = 1; off < 32; off <<= 1) d += __shfl_xor(d, off);
    if (lane == 0) pos2[p] = 2.0f * d;
    return;
  }

  // c-section: blocks 1024..1279, verified chunk mapping (i2 in [0, 65536))
  if (blockIdx.x == 1024 && threadIdx.x == 0) out[0] = 0.0f;
  const int i2   = (blockIdx.x - 1024) * 256 + threadIdx.x;
  const int lane = i2 & 63, g = i2 >> 6;
  const int ct = g >> 1, cc = g & 1;
  const int ln = lane & 15, lq = lane >> 4;
  const int row = ct * 16 + ln;
  const int k0 = cc * 64 + lq * 8;
  const float* src = (row < BHALF) ? (c_i + (size_t)row * DC) : (c_j + (size_t)(row - BHALF) * DC);
  uint8_t* dst = cbT + (size_t)i2 * 16;

  floatx4 a0 = *(const floatx4*)(src + k0);
  floatx4 a1 = *(const floatx4*)(src + k0 + 4);
  floatx4 b0 = *(const floatx4*)(src + k0 + 32);
  floatx4 b1 = *(const floatx4*)(src + k0 + 36);
  uint4v o;
  o.x = pk4_e4m3(a0[0], a0[1], a0[2], a0[3]);
  o.y = pk4_e4m3(a1[0], a1[1], a1[2], a1[3]);
  o.z = pk4_e4m3(b0[0], b0[1], b0[2], b0[3]);
  o.w = pk4_e4m3(b1[0], b1[1], b1[2], b1[3]);
  *(uint4v*)dst = o;
}

// stage one 32-col iter (20 KB: 16 KB z + 4 KB c) into buf. Wave w stages 4 z
// chunk-groups (g=4w..4w+3, g = tile*8+cc contiguous) + 1 c group. L = 5 loads/wave.
__device__ __forceinline__ void stage32(const uint8_t* __restrict__ zbT,
                                        const uint8_t* __restrict__ cbT,
                                        uint8_t* buf, int cb, int itc, int w, int lane) {
  const uint8_t* zsrc = zbT + ((size_t)cb * 64 + itc * 16 + 4 * w) * 1024 + lane * 16;
#pragma unroll
  for (int q = 0; q < 4; ++q)
    gll(zsrc + q * 1024, buf + (4 * w + q) * 1024 + lane * 16);
  const uint8_t* csrc = cbT + ((size_t)cb * 16 + itc * 4 + w) * 1024 + lane * 16;
  gll(csrc, buf + 16384 + w * 1024 + lane * 16);
}

// ---------------- fused symmetric flash-lse: upper-triangle 128x128 blocks ----------------
// R26: 32x32x64 scaled MFMA. Nine rounds isolated the invariant wall: B-operand bytes
// per output elem (40 B with 16x16x128 @32 rows/wave) -> ~5.2 MB/CU through the ~85 B/cy
// LDS port = ~26 us (or ~39 us via L2 for the no-LDS variant) = the universal ~44 us.
// 32x32x64 halves it to 20 B/elem at UNCHANGED A-residency (8z+2c operands = 80 VGPR;
// the 64-row attempts R4/R6/R7 needed 160+ and spilled/latency-bound). Wave = 32 rows x
// 32 cols/iter; block 128x128, 4 iters; 3 LDS buffers (62 KB, 2 blocks/CU = measured
// occupancy of the 44us kernel), R1-verified pipeline (stage-ahead, counted vmcnt,
// 2 barriers/iter). C/D: col=lane&31, row=(reg&3)+8*(reg>>2)+4*(lane>>5) [m74/m101].
// A and B built by the identical chunk-extraction -> k-permutation cancels positionally.
__launch_bounds__(256, 3)
__global__ void fused_kernel(const uint8_t* __restrict__ zbT, const uint8_t* __restrict__ cbT,
                             float* __restrict__ RP, float* __restrict__ CP) {
  __shared__ __align__(16) uint8_t S[3][20480];   // 3 x (16 KB z + 4 KB c)
  __shared__ float colbuf[4 * 128];               // 2 KB

  // triangular decode: t -> (rb, cb), rb <= cb, 2080 blocks
  const int t = blockIdx.x;
  const int u = 2079 - t;
  int k = (int)((__builtin_sqrtf(8.0f * (float)u + 1.0f) - 1.0f) * 0.5f);
  while ((k + 1) * (k + 2) / 2 <= u) ++k;
  while (k * (k + 1) / 2 > u) --k;
  const int j4 = u - k * (k + 1) / 2;
  const int rb = 63 - k;
  const int cb = 63 - j4;
  const bool diagBlk = (rb == cb);
  const bool pairBlk = (cb == rb + 32);

  const int tid  = threadIdx.x;
  const int w    = tid >> 6;      // 0..3
  const int lane = tid & 63;
  const int c32  = lane & 31;     // col within 32 (B) / row within 32 (A)
  const int hi   = lane >> 5;
  const int lnr  = lane & 15;
  const int tsel = c32 >> 4;      // which 16-tile of the pair
  const int hi4  = 4 * hi;

  const int row_w = rb * 128 + w * 32;     // wave's 32 rows

  // A operands (resident): z 8 x v8i32 (K=512) + c 2 x v8i32 (K=128) = 80 VGPR.
  // Per-lane: row r = c32 of this wave's 32; same chunk-extraction as B below.
  int8v a_z[8], a_c[2];
  {
    const int rt0 = rb * 8 + 2 * w;
    const uint8_t* pa = zbT + (size_t)(rt0 + tsel) * 8192 + lnr * 16 + hi * 512;
#pragma unroll
    for (int kk = 0; kk < 8; ++kk)
      a_z[kk] = mk8(*(const ulong2v*)(pa + kk * 1024),
                    *(const ulong2v*)(pa + kk * 1024 + 256));
    const uint8_t* pc = cbT + (size_t)(rt0 + tsel) * 2048 + lnr * 16 + hi * 512;
    a_c[0] = mk8(*(const ulong2v*)pc, *(const ulong2v*)(pc + 256));
    a_c[1] = mk8(*(const ulong2v*)(pc + 1024), *(const ulong2v*)(pc + 1024 + 256));
  }

  float l_[16];
#pragma unroll
  for (int j = 0; j < 16; ++j) l_[j] = 0.0f;

  stage32(zbT, cbT, &S[0][0], cb, 0, w, lane);
  stage32(zbT, cbT, &S[1][0], cb, 1, w, lane);

#pragma unroll
  for (int itc = 0; itc < 4; ++itc) {
    // stage iter itc+2 into S[(itc+2)%3] (= S[(itc-1)%3], safe: its compute ended
    // before iter itc-1's end-barrier which all waves passed), then counted wait.
    if (itc < 2) { stage32(zbT, cbT, &S[(itc + 2) % 3][0], cb, itc + 2, w, lane); WAITV(10); }
    else if (itc == 2) { WAITV(5); }
    else { WAITV(0); }
    BARRIER();   // all waves' iter-itc stages landed

    float lcv = 0.0f;
    // wave-uniform skip: diag blocks, col-groups fully below this wave's 32 rows
    if (!(diagBlk && itc < w)) {
      const uint8_t* zb  = &S[itc % 3][0];
      const uint8_t* cS_ = zb + 16384;
      const int zo = tsel * 8192 + lnr * 16 + hi * 512;
      const int co = tsel * 2048 + lnr * 16 + hi * 512;

      f32x16 ac = {0.f,0.f,0.f,0.f,0.f,0.f,0.f,0.f,0.f,0.f,0.f,0.f,0.f,0.f,0.f,0.f};
      f32x16 az = {0.f,0.f,0.f,0.f,0.f,0.f,0.f,0.f,0.f,0.f,0.f,0.f,0.f,0.f,0.f,0.f};

      __builtin_amdgcn_s_setprio(1);
#pragma unroll
      for (int kk = 0; kk < 2; ++kk) {
        const int8v bc = mk8(*(const ulong2v*)(cS_ + co + kk * 1024),
                             *(const ulong2v*)(cS_ + co + kk * 1024 + 256));
        ac = MFMAS32(a_c[kk], bc, ac);
      }
#pragma unroll
      for (int kk = 0; kk < 8; ++kk) {
        const int8v bz = mk8(*(const ulong2v*)(zb + zo + kk * 1024),
                             *(const ulong2v*)(zb + zo + kk * 1024 + 256));
        az = MFMAS32(a_z[kk], bz, az);
      }
      __builtin_amdgcn_s_setprio(0);

      // masks: local col = itc*32 + c32, local row = w*32 + rowv
      const int dL = itc * 32 + c32 - w * 32;
      const bool pt = pairBlk && (itc == w);
#pragma unroll
      for (int j = 0; j < 16; ++j) {
        const int rowv = (j & 3) + 8 * (j >> 2) + hi4;
        float tv = fmaxf(ac[j], TEMPV);
        float sv = az[j] * __builtin_amdgcn_rcpf(tv);
        float e  = __builtin_amdgcn_exp2f(__builtin_fmaf(sv, LOG2E, -FM2));
        if (diagBlk && dL <= rowv) e = 0.0f;   // diag + lower half
        if (pt && c32 == rowv) e = 0.0f;       // pair exclusion
        l_[j] += e;
        lcv += e;
      }
    }

    // col partial for this 32-col group over this wave's 32 rows (always written:
    // skipped diag iters must store 0, workspace is poisoned not zeroed)
    float v = lcv;
    v += __shfl_xor(v, 32);
    if (lane < 32) colbuf[w * 128 + itc * 32 + lane] = v;

    BARRIER();   // all waves done reading S[itc%3] before its buffer is re-staged
  }

  __syncthreads();   // full drain (colbuf ds_writes) before cross-wave read

  // row partials -> RP[row][cb]: reduce each reg over the 32-lane col group
#pragma unroll
  for (int j = 0; j < 16; ++j) {
    float ll = l_[j];
#pragma unroll
    for (int off = 1; off < 32; off <<= 1) ll += __shfl_xor(ll, off);
    if (c32 == 0) {
      const int rowv = (j & 3) + 8 * (j >> 2) + hi4;
      RP[(size_t)(row_w + rowv) * 64 + cb] = ll;
    }
  }

  // col partials: sum the 4 per-wave rows of colbuf -> CP[col][rb]
  if (tid < 128) {
    float s = 0.0f;
#pragma unroll
    for (int ww = 0; ww < 4; ++ww) s += colbuf[ww * 128 + tid];
    CP[(size_t)(cb * 128 + tid) * 64 + rb] = s;
  }
}

// ---------------- finalize: triangular partial merge + pos + reduction ----------------
__global__ void finalize_kernel(const float* __restrict__ RP, const float* __restrict__ CP,
                                const float* __restrict__ pos2, float* __restrict__ out) {
  const int tid  = threadIdx.x;
  const int w    = tid >> 6;
  const int lane = tid & 63;
  const int row  = blockIdx.x * 16 + w;
  const int R    = row >> 7;

  float v = 0.0f;
  if (lane >= R) v += RP[(size_t)row * 64 + lane];
  if (lane <= R) v += CP[(size_t)row * 64 + lane];
#pragma unroll
  for (int off = 1; off < 64; off <<= 1) v += __shfl_xor(v, off);

  __shared__ float red[16];
  if (lane == 0) {
    float pos  = pos2[row & (BHALF - 1)];
    float lneg = FIXM + __logf(v);
    float hi = fmaxf(lneg, pos), lo = fminf(lneg, pos);
    float lse = hi + __logf(1.0f + __expf(lo - hi));
    red[w] = lse - pos;
  }
  __syncthreads();
  if (tid == 0) {
    float s = 0.0f;
#pragma unroll
    for (int i = 0; i < 16; ++i) s += red[i];
    atomicAdd(out, s * (1.0f / NTOT));
  }
}

extern "C" void kernel_launch(void* const* d_in, const int* in_sizes, int n_in,
                              void* d_out, int out_size, void* d_ws, size_t ws_size,
                              hipStream_t stream) {
  const float* z_i = (const float*)d_in[0];
  const float* z_j = (const float*)d_in[1];
  const float* c_i = (const float*)d_in[2];
  const float* c_j = (const float*)d_in[3];

  uint8_t* zbT = (uint8_t*)d_ws;                        // 4 MB fp8 z (tiled)
  uint8_t* cbT = zbT + (size_t)NTOT * DZ;               // 1 MB fp8 c (tiled)
  float* RP   = (float*)(cbT + (size_t)NTOT * DC);      // 2 MB
  float* CP   = RP + (size_t)NTOT * 64;                 // 2 MB
  float* pos2 = CP + (size_t)NTOT * 64;                 // 16 KB

  convert_kernel<<<1280, 256, 0, stream>>>(z_i, z_j, c_i, c_j, zbT, cbT, pos2, (float*)d_out);
  fused_kernel<<<2080, 256, 0, stream>>>(zbT, cbT, RP, CP);
  finalize_kernel<<<512, 1024, 0, stream>>>(RP, CP, pos2, (float*)d_out);
}

// Round 11
// 127.457 us; speedup vs baseline: 1.0289x; 1.0289x over previous
//
#include <hip/hip_runtime.h>
#include <stdint.h>

#define NTOT 8192
#define BHALF 4096
#define DZ 512
#define DC 128
#define TEMPV 0.5f
#define FIXM 16.0f
#define LOG2E 1.44269504f
#define FM2 23.08312065f   // FIXM * LOG2E
#define SCALE1 0x7F7F7F7F  // e8m0 unit scales

typedef __attribute__((ext_vector_type(4))) float f32x4;
typedef __attribute__((ext_vector_type(16))) float f32x16;
typedef __attribute__((ext_vector_type(4))) float floatx4;
typedef __attribute__((ext_vector_type(2))) unsigned long ulong2v;  // 16B chunk
typedef __attribute__((ext_vector_type(8))) int int8v;              // 32B MFMA operand
typedef __attribute__((ext_vector_type(4))) unsigned int uint4v;

// MX-scaled fp8 MFMA, 32x32x64, unit scales. cbsz=0/blgp=0 -> FP8 e4m3 A and B.
#define MFMAS32(a, b, c) \
  __builtin_amdgcn_mfma_scale_f32_32x32x64_f8f6f4((a), (b), (c), 0, 0, 0, SCALE1, 0, SCALE1)

// counted vmcnt + raw barrier (no vmcnt(0) drain in the main loop)
#define WAITV(N) asm volatile("s_waitcnt vmcnt(" #N ")" ::: "memory")
#define BARRIER() asm volatile("s_barrier" ::: "memory")

__device__ __forceinline__ uint32_t pk4_e4m3(float f0, float f1, float f2, float f3) {
  int w = 0;
  w = __builtin_amdgcn_cvt_pk_fp8_f32(f0, f1, w, false);
  w = __builtin_amdgcn_cvt_pk_fp8_f32(f2, f3, w, true);
  return (uint32_t)w;
}

__device__ __forceinline__ int8v mk8(ulong2v lo, ulong2v hi) {
  int8v r;
  ((ulong2v*)&r)[0] = lo;
  ((ulong2v*)&r)[1] = hi;
  return r;
}

__device__ __forceinline__ void gll(const uint8_t* src, uint8_t* dst) {
  __builtin_amdgcn_global_load_lds((const __attribute__((address_space(1))) void*)src,
                                   (__attribute__((address_space(3))) void*)dst, 16, 0, 0);
}

// ---------------- convert: fp32 -> fp8 e4m3 (frag-pair-tiled) + fused pos dots ----------------
// R21 single-pass version (verified): one wave per pair-row; z read once; pos dot via
// shfl_xor(.,32) cross-half products. c-section verified mapping.
__global__ void convert_kernel(const float* __restrict__ z_i, const float* __restrict__ z_j,
                               const float* __restrict__ c_i, const float* __restrict__ c_j,
                               uint8_t* __restrict__ zbT, uint8_t* __restrict__ cbT,
                               float* __restrict__ pos2, float* __restrict__ out) {
  if (blockIdx.x < 1024) {
    const int p    = blockIdx.x * 4 + (threadIdx.x >> 6);   // 0..4095
    const int lane = threadIdx.x & 63;
    const int half = lane >> 5;          // 0: z_i row p, 1: z_j row p (global row p+4096)
    const int l    = lane & 31;
    const int cc   = l >> 2;
    const int lq   = l & 3;
    const int k0   = cc * 64 + lq * 8;

    const float* src = half ? (z_j + (size_t)p * DZ) : (z_i + (size_t)p * DZ);
    floatx4 a0 = *(const floatx4*)(src + k0);
    floatx4 a1 = *(const floatx4*)(src + k0 + 4);
    floatx4 b0 = *(const floatx4*)(src + k0 + 32);
    floatx4 b1 = *(const floatx4*)(src + k0 + 36);

    uint4v o;
    o.x = pk4_e4m3(a0[0], a0[1], a0[2], a0[3]);
    o.y = pk4_e4m3(a1[0], a1[1], a1[2], a1[3]);
    o.z = pk4_e4m3(b0[0], b0[1], b0[2], b0[3]);
    o.w = pk4_e4m3(b1[0], b1[1], b1[2], b1[3]);
    const int row = half ? (p + BHALF) : p;
    const size_t ci = (((size_t)(row >> 4) * 8 + cc) * 64 + (size_t)lq * 16 + (row & 15));
    *(uint4v*)(zbT + ci * 16) = o;

    float d = 0.0f;
#pragma unroll
    for (int m = 0; m < 4; ++m) d = __builtin_fmaf(a0[m], __shfl_xor(a0[m], 32), d);
#pragma unroll
    for (int m = 0; m < 4; ++m) d = __builtin_fmaf(a1[m], __shfl_xor(a1[m], 32), d);
#pragma unroll
    for (int m = 0; m < 4; ++m) d = __builtin_fmaf(b0[m], __shfl_xor(b0[m], 32), d);
#pragma unroll
    for (int m = 0; m < 4; ++m) d = __builtin_fmaf(b1[m], __shfl_xor(b1[m], 32), d);
#pragma unroll
    for (int off = 1; off < 32; off <<= 1) d += __shfl_xor(d, off);
    if (lane == 0) pos2[p] = 2.0f * d;
    return;
  }

  // c-section: blocks 1024..1279, verified chunk mapping (i2 in [0, 65536))
  if (blockIdx.x == 1024 && threadIdx.x == 0) out[0] = 0.0f;
  const int i2   = (blockIdx.x - 1024) * 256 + threadIdx.x;
  const int lane = i2 & 63, g = i2 >> 6;
  const int ct = g >> 1, cc = g & 1;
  const int ln = lane & 15, lq = lane >> 4;
  const int row = ct * 16 + ln;
  const int k0 = cc * 64 + lq * 8;
  const float* src = (row < BHALF) ? (c_i + (size_t)row * DC) : (c_j + (size_t)(row - BHALF) * DC);
  uint8_t* dst = cbT + (size_t)i2 * 16;

  floatx4 a0 = *(const floatx4*)(src + k0);
  floatx4 a1 = *(const floatx4*)(src + k0 + 4);
  floatx4 b0 = *(const floatx4*)(src + k0 + 32);
  floatx4 b1 = *(const floatx4*)(src + k0 + 36);
  uint4v o;
  o.x = pk4_e4m3(a0[0], a0[1], a0[2], a0[3]);
  o.y = pk4_e4m3(a1[0], a1[1], a1[2], a1[3]);
  o.z = pk4_e4m3(b0[0], b0[1], b0[2], b0[3]);
  o.w = pk4_e4m3(b1[0], b1[1], b1[2], b1[3]);
  *(uint4v*)dst = o;
}

// stage one 32-col iter (20 KB: 16 KB z + 4 KB c) into buf. Wave w stages 4 z
// chunk-groups (g=4w..4w+3, g = tile*8+cc contiguous) + 1 c group. L = 5 loads/wave.
// (byte layout verified by R10's passing refcheck)
__device__ __forceinline__ void stage32(const uint8_t* __restrict__ zbT,
                                        const uint8_t* __restrict__ cbT,
                                        uint8_t* buf, int cb, int itc, int w, int lane) {
  const uint8_t* zsrc = zbT + ((size_t)cb * 64 + itc * 16 + 4 * w) * 1024 + lane * 16;
#pragma unroll
  for (int q = 0; q < 4; ++q)
    gll(zsrc + q * 1024, buf + (4 * w + q) * 1024 + lane * 16);
  const uint8_t* csrc = cbT + ((size_t)cb * 16 + itc * 4 + w) * 1024 + lane * 16;
  gll(csrc, buf + 16384 + w * 1024 + lane * 16);
}

// ---------------- fused symmetric flash-lse: upper-triangle 128x128 blocks ----------------
// R27: de-confounded 32x32x64. R10 bundled the shape change (B-bytes/elem halved, the
// 10-round invariant wall) with TWO regressions the counters exposed: LDS 62KB -> 2
// blocks/CU (occupancy 17% vs the 44us kernel's 24%), and ONE serial 8-MFMA z-chain
// (~400cy latency, unhidable at 2 waves/SIMD). This round keeps the shape, fixes both:
// (a) 2 LDS buffers (42KB -> 3 blocks/CU, same occupancy as the 43.9us baseline) with
// stage-after-compute double-buffering (WAITV(5) counted, no vmcnt(0) mid-loop);
// (b) z-accumulator split az0/az1 -> two independent 4-deep chains (+16 AGPR).
// C/D layout + stage/A-frag byte mapping byte-identical to R10 (refcheck-verified).
__launch_bounds__(256, 3)
__global__ void fused_kernel(const uint8_t* __restrict__ zbT, const uint8_t* __restrict__ cbT,
                             float* __restrict__ RP, float* __restrict__ CP) {
  __shared__ __align__(16) uint8_t S[2][20480];   // 2 x (16 KB z + 4 KB c) = 40 KB
  __shared__ float colbuf[4 * 128];               // 2 KB

  // triangular decode: t -> (rb, cb), rb <= cb, 2080 blocks
  const int t = blockIdx.x;
  const int u = 2079 - t;
  int k = (int)((__builtin_sqrtf(8.0f * (float)u + 1.0f) - 1.0f) * 0.5f);
  while ((k + 1) * (k + 2) / 2 <= u) ++k;
  while (k * (k + 1) / 2 > u) --k;
  const int j4 = u - k * (k + 1) / 2;
  const int rb = 63 - k;
  const int cb = 63 - j4;
  const bool diagBlk = (rb == cb);
  const bool pairBlk = (cb == rb + 32);

  const int tid  = threadIdx.x;
  const int w    = tid >> 6;      // 0..3
  const int lane = tid & 63;
  const int c32  = lane & 31;     // col within 32 (B) / row within 32 (A)
  const int hi   = lane >> 5;
  const int lnr  = lane & 15;
  const int tsel = c32 >> 4;      // which 16-tile of the pair
  const int hi4  = 4 * hi;

  const int row_w = rb * 128 + w * 32;     // wave's 32 rows

  // A operands (resident): z 8 x v8i32 (K=512) + c 2 x v8i32 (K=128) = 80 VGPR.
  int8v a_z[8], a_c[2];
  {
    const int rt0 = rb * 8 + 2 * w;
    const uint8_t* pa = zbT + (size_t)(rt0 + tsel) * 8192 + lnr * 16 + hi * 512;
#pragma unroll
    for (int kk = 0; kk < 8; ++kk)
      a_z[kk] = mk8(*(const ulong2v*)(pa + kk * 1024),
                    *(const ulong2v*)(pa + kk * 1024 + 256));
    const uint8_t* pc = cbT + (size_t)(rt0 + tsel) * 2048 + lnr * 16 + hi * 512;
    a_c[0] = mk8(*(const ulong2v*)pc, *(const ulong2v*)(pc + 256));
    a_c[1] = mk8(*(const ulong2v*)(pc + 1024), *(const ulong2v*)(pc + 1024 + 256));
  }

  float l_[16];
#pragma unroll
  for (int j = 0; j < 16; ++j) l_[j] = 0.0f;

  stage32(zbT, cbT, &S[0][0], cb, 0, w, lane);
  stage32(zbT, cbT, &S[1][0], cb, 1, w, lane);

#pragma unroll
  for (int itc = 0; itc < 4; ++itc) {
    // wait for tile itc (allow the one newer stage, 5 loads/wave, to stay in flight)
    if (itc < 3) { WAITV(5); } else { WAITV(0); }
    BARRIER();   // all waves' iter-itc stages landed

    float lcv = 0.0f;
    // wave-uniform skip: diag blocks, col-groups fully below this wave's 32 rows
    if (!(diagBlk && itc < w)) {
      const uint8_t* zb  = &S[itc & 1][0];
      const uint8_t* cS_ = zb + 16384;
      const int zo = tsel * 8192 + lnr * 16 + hi * 512;
      const int co = tsel * 2048 + lnr * 16 + hi * 512;

      f32x16 ac  = {0.f,0.f,0.f,0.f,0.f,0.f,0.f,0.f,0.f,0.f,0.f,0.f,0.f,0.f,0.f,0.f};
      f32x16 az0 = {0.f,0.f,0.f,0.f,0.f,0.f,0.f,0.f,0.f,0.f,0.f,0.f,0.f,0.f,0.f,0.f};
      f32x16 az1 = {0.f,0.f,0.f,0.f,0.f,0.f,0.f,0.f,0.f,0.f,0.f,0.f,0.f,0.f,0.f,0.f};

      __builtin_amdgcn_s_setprio(1);
#pragma unroll
      for (int kk = 0; kk < 2; ++kk) {
        const int8v bc = mk8(*(const ulong2v*)(cS_ + co + kk * 1024),
                             *(const ulong2v*)(cS_ + co + kk * 1024 + 256));
        ac = MFMAS32(a_c[kk], bc, ac);
      }
      // two independent 4-deep z chains (R10's single 8-chain was latency-bound)
#pragma unroll
      for (int kk = 0; kk < 4; ++kk) {
        const int8v bz = mk8(*(const ulong2v*)(zb + zo + kk * 1024),
                             *(const ulong2v*)(zb + zo + kk * 1024 + 256));
        az0 = MFMAS32(a_z[kk], bz, az0);
      }
#pragma unroll
      for (int kk = 4; kk < 8; ++kk) {
        const int8v bz = mk8(*(const ulong2v*)(zb + zo + kk * 1024),
                             *(const ulong2v*)(zb + zo + kk * 1024 + 256));
        az1 = MFMAS32(a_z[kk], bz, az1);
      }
      __builtin_amdgcn_s_setprio(0);

      // masks: local col = itc*32 + c32, local row = w*32 + rowv
      const int dL = itc * 32 + c32 - w * 32;
      const bool pt = pairBlk && (itc == w);
#pragma unroll
      for (int j = 0; j < 16; ++j) {
        const int rowv = (j & 3) + 8 * (j >> 2) + hi4;
        float tv = fmaxf(ac[j], TEMPV);
        float sv = (az0[j] + az1[j]) * __builtin_amdgcn_rcpf(tv);
        float e  = __builtin_amdgcn_exp2f(__builtin_fmaf(sv, LOG2E, -FM2));
        if (diagBlk && dL <= rowv) e = 0.0f;   // diag + lower half
        if (pt && c32 == rowv) e = 0.0f;       // pair exclusion
        l_[j] += e;
        lcv += e;
      }
    }

    // col partial for this 32-col group over this wave's 32 rows (always written:
    // skipped diag iters must store 0, workspace is poisoned not zeroed)
    float v = lcv;
    v += __shfl_xor(v, 32);
    if (lane < 32) colbuf[w * 128 + itc * 32 + lane] = v;

    BARRIER();   // all waves done reading S[itc&1] before it is re-staged below

    if (itc + 2 < 4)
      stage32(zbT, cbT, &S[itc & 1][0], cb, itc + 2, w, lane);
  }

  __syncthreads();   // full drain (colbuf ds_writes) before cross-wave read

  // row partials -> RP[row][cb]: reduce each reg over the 32-lane col group
#pragma unroll
  for (int j = 0; j < 16; ++j) {
    float ll = l_[j];
#pragma unroll
    for (int off = 1; off < 32; off <<= 1) ll += __shfl_xor(ll, off);
    if (c32 == 0) {
      const int rowv = (j & 3) + 8 * (j >> 2) + hi4;
      RP[(size_t)(row_w + rowv) * 64 + cb] = ll;
    }
  }

  // col partials: sum the 4 per-wave rows of colbuf -> CP[col][rb]
  if (tid < 128) {
    float s = 0.0f;
#pragma unroll
    for (int ww = 0; ww < 4; ++ww) s += colbuf[ww * 128 + tid];
    CP[(size_t)(cb * 128 + tid) * 64 + rb] = s;
  }
}

// ---------------- finalize: triangular partial merge + pos + reduction ----------------
__global__ void finalize_kernel(const float* __restrict__ RP, const float* __restrict__ CP,
                                const float* __restrict__ pos2, float* __restrict__ out) {
  const int tid  = threadIdx.x;
  const int w    = tid >> 6;
  const int lane = tid & 63;
  const int row  = blockIdx.x * 16 + w;
  const int R    = row >> 7;

  float v = 0.0f;
  if (lane >= R) v += RP[(size_t)row * 64 + lane];
  if (lane <= R) v += CP[(size_t)row * 64 + lane];
#pragma unroll
  for (int off = 1; off < 64; off <<= 1) v += __shfl_xor(v, off);

  __shared__ float red[16];
  if (lane == 0) {
    float pos  = pos2[row & (BHALF - 1)];
    float lneg = FIXM + __logf(v);
    float hi = fmaxf(lneg, pos), lo = fminf(lneg, pos);
    float lse = hi + __logf(1.0f + __expf(lo - hi));
    red[w] = lse - pos;
  }
  __syncthreads();
  if (tid == 0) {
    float s = 0.0f;
#pragma unroll
    for (int i = 0; i < 16; ++i) s += red[i];
    atomicAdd(out, s * (1.0f / NTOT));
  }
}

extern "C" void kernel_launch(void* const* d_in, const int* in_sizes, int n_in,
                              void* d_out, int out_size, void* d_ws, size_t ws_size,
                              hipStream_t stream) {
  const float* z_i = (const float*)d_in[0];
  const float* z_j = (const float*)d_in[1];
  const float* c_i = (const float*)d_in[2];
  const float* c_j = (const float*)d_in[3];

  uint8_t* zbT = (uint8_t*)d_ws;                        // 4 MB fp8 z (tiled)
  uint8_t* cbT = zbT + (size_t)NTOT * DZ;               // 1 MB fp8 c (tiled)
  float* RP   = (float*)(cbT + (size_t)NTOT * DC);      // 2 MB
  float* CP   = RP + (size_t)NTOT * 64;                 // 2 MB
  float* pos2 = CP + (size_t)NTOT * 64;                 // 16 KB

  convert_kernel<<<1280, 256, 0, stream>>>(z_i, z_j, c_i, c_j, zbT, cbT, pos2, (float*)d_out);
  fused_kernel<<<2080, 256, 0, stream>>>(zbT, cbT, RP, CP);
  finalize_kernel<<<512, 1024, 0, stream>>>(RP, CP, pos2, (float*)d_out);
}